// Round 6
// baseline (4453.286 us; speedup 1.0000x reference)
//
#include <hip/hip_runtime.h>
#include <hip/hip_bf16.h>

// GraphSAGE 3-layer, gather-based CSR + bf16-MFMA GEMMs.
// ROUND-6 PROBE: suspect kernels carry a runtime `rep` loop re-doing their
// full work (idempotent). Inflated durations push them past the ~210 µs
// harness-fill wall so the top-5 rocprof table shows per-kernel dur+counters.
//   gemm0 x12, gather1 x24, gemm1 x48, final x48, scan3 x24, gather0 x1.
// True per-unit cost = dur/REP. Everything else identical to round 4.

typedef short bf16x8 __attribute__((ext_vector_type(8)));
typedef float f32x4 __attribute__((ext_vector_type(4)));

static __device__ __forceinline__ unsigned short f2bf(float f) {
  unsigned u = __float_as_uint(f);
  unsigned r = u + 0x7FFFu + ((u >> 16) & 1u);  // RNE
  return (unsigned short)(r >> 16);
}

// ---------------- CSR build ----------------
__global__ __launch_bounds__(256) void hist3_k(
    const int* __restrict__ d0, const int* __restrict__ d1, const int* __restrict__ d2,
    int* __restrict__ c0, int* __restrict__ c1, int* __restrict__ c2,
    int E0, int E1, int E2) {
  int t = blockIdx.x * 256 + threadIdx.x;
  if (t < E0) atomicAdd(&c0[d0[t]], 1);
  else if (t < E0 + E1) atomicAdd(&c1[d1[t - E0]], 1);
  else if (t < E0 + E1 + E2) atomicAdd(&c2[d2[t - E0 - E1]], 1);
}

__global__ __launch_bounds__(1024) void scan3_k(
    const int* __restrict__ c0, int* __restrict__ r0, int* __restrict__ u0,
    const int* __restrict__ c1, int* __restrict__ r1, int* __restrict__ u1,
    const int* __restrict__ c2, int* __restrict__ r2, int* __restrict__ u2,
    int n0, int n1, int n2, int rep) {
  const int* cnt; int* row; int* cur; int n;
  if (blockIdx.x == 0)      { cnt = c0; row = r0; cur = u0; n = n0; }
  else if (blockIdx.x == 1) { cnt = c1; row = r1; cur = u1; n = n1; }
  else                      { cnt = c2; row = r2; cur = u2; n = n2; }
  __shared__ int sums[1024];
  const int t = threadIdx.x;
  const int chunk = (n + 1023) / 1024;
  const int lo = t * chunk;
  const int hi = min(lo + chunk, n);
#pragma unroll 1
  for (int it = 0; it < rep; ++it) {
    __syncthreads();
    int s = 0;
    for (int i = lo; i < hi; ++i) s += cnt[i];
    sums[t] = s;
    __syncthreads();
    for (int off = 1; off < 1024; off <<= 1) {
      int v = (t >= off) ? sums[t - off] : 0;
      __syncthreads();
      sums[t] += v;
      __syncthreads();
    }
    int prefix = (t == 0) ? 0 : sums[t - 1];
    for (int i = lo; i < hi; ++i) {
      row[i] = prefix;
      cur[i] = prefix;
      prefix += cnt[i];
    }
    if (t == 1023) row[n] = sums[1023];
  }
}

__global__ __launch_bounds__(256) void fill3_k(
    const int* __restrict__ s0, const int* __restrict__ d0,
    const int* __restrict__ s1, const int* __restrict__ d1,
    const int* __restrict__ s2, const int* __restrict__ d2,
    int* __restrict__ u0, int* __restrict__ u1, int* __restrict__ u2,
    int* __restrict__ o0, int* __restrict__ o1, int* __restrict__ o2,
    int E0, int E1, int E2) {
  int t = blockIdx.x * 256 + threadIdx.x;
  if (t < E0) {
    int pos = atomicAdd(&u0[d0[t]], 1);
    o0[pos] = s0[t];
  } else if (t < E0 + E1) {
    int e = t - E0;
    int pos = atomicAdd(&u1[d1[e]], 1);
    o1[pos] = s1[e];
  } else if (t < E0 + E1 + E2) {
    int e = t - E0 - E1;
    int pos = atomicAdd(&u2[d2[e]], 1);
    o2[pos] = s2[e];
  }
}

// ------------- gather-mean + self-row conversion, bf16 A-matrix out -------------
template <int D, int PITCH, int XOFF>
__global__ __launch_bounds__(256) void gather_fused_k(
    const float* __restrict__ x, const float* __restrict__ xt,
    const int* __restrict__ ss, const int* __restrict__ rs,
    unsigned short* __restrict__ am, int n, int rep) {
  int idx = blockIdx.x * 256 + threadIdx.x;
  int w = idx >> 6;
  int f = idx & 63;
  if (w >= n) return;
  const int lo = rs[w];
  const int hi = rs[w + 1];
  constexpr int NR = (D + 63) / 64;
#pragma unroll 1
  for (int it = 0; it < rep; ++it) {
    float acc[NR];
#pragma unroll
    for (int r = 0; r < NR; ++r) acc[r] = 0.f;
    int e = lo;
    for (; e + 4 <= hi; e += 4) {
      const float* p0 = x + (size_t)ss[e] * D;
      const float* p1 = x + (size_t)ss[e + 1] * D;
      const float* p2 = x + (size_t)ss[e + 2] * D;
      const float* p3 = x + (size_t)ss[e + 3] * D;
#pragma unroll
      for (int r = 0; r < NR; ++r) {
        int k = f + 64 * r;
        if (k < D) acc[r] += (p0[k] + p1[k]) + (p2[k] + p3[k]);
      }
    }
    for (; e < hi; ++e) {
      const float* p0 = x + (size_t)ss[e] * D;
#pragma unroll
      for (int r = 0; r < NR; ++r) {
        int k = f + 64 * r;
        if (k < D) acc[r] += p0[k];
      }
    }
    const float inv = 1.f / (float)max(hi - lo, 1);
    unsigned short* arow = am + (size_t)w * PITCH;
#pragma unroll
    for (int r = 0; r < NR; ++r) {
      int k = f + 64 * r;
      if (k < D) arow[k] = f2bf(acc[r] * inv);
    }
    const float* xrow = xt + (size_t)w * D;
#pragma unroll
    for (int r = 0; r < NR; ++r) {
      int k = f + 64 * r;
      if (k < D) arow[XOFF + k] = f2bf(xrow[k]);
    }
  }
}

// ------------- B packing for both layers -------------
__global__ __launch_bounds__(256) void pack2_k(
    const float* __restrict__ Wl0, const float* __restrict__ Wr0,
    unsigned short* __restrict__ bm0,
    const float* __restrict__ Wl1, const float* __restrict__ Wr1,
    unsigned short* __restrict__ bm1) {
  int b = blockIdx.x;
  int n = threadIdx.x;
  if (b < 224) {
    int k = b;
    float v = 0.f;
    if (k < 100) v = Wl0[(size_t)k * 256 + n];
    else if (k >= 112 && k < 212) v = Wr0[(size_t)(k - 112) * 256 + n];
    bm0[(((size_t)(k >> 3) * 256) + n) * 8 + (k & 7)] = f2bf(v);
  } else {
    int k = b - 224;
    float v = (k < 256) ? Wl1[(size_t)k * 256 + n] : Wr1[(size_t)(k - 256) * 256 + n];
    bm1[(((size_t)(k >> 3) * 256) + n) * 8 + (k & 7)] = f2bf(v);
  }
}

// ------------- MFMA GEMM -------------
template <int KPAD, int MBLK, bool RELU>
__global__ __launch_bounds__(256) void gemm_mfma_k(
    const unsigned short* __restrict__ A, const unsigned short* __restrict__ Bp,
    const float* __restrict__ bias, float* __restrict__ out, int M, int rep) {
  constexpr int LDA = KPAD + 8;
  constexpr int CPR = KPAD / 8;
  constexpr int RT = MBLK / 16;
  constexpr int NKC = KPAD / 32;
  __shared__ unsigned short As[MBLK * LDA];

  const int row0 = blockIdx.x * MBLK;
  const int wid = threadIdx.x >> 6;
  const int l = threadIdx.x & 63;
  const int l15 = l & 15;
  const int lhi = l >> 4;

#pragma unroll 1
  for (int it = 0; it < rep; ++it) {
    __syncthreads();
    for (int t = threadIdx.x; t < MBLK * CPR; t += 256) {
      int r = t / CPR;
      int c = t - r * CPR;
      const uint4 v = *reinterpret_cast<const uint4*>(A + (size_t)(row0 + r) * KPAD + c * 8);
      *reinterpret_cast<uint4*>(&As[r * LDA + c * 8]) = v;
    }
    __syncthreads();

    f32x4 acc[RT][4];
#pragma unroll
    for (int rt = 0; rt < RT; ++rt)
#pragma unroll
      for (int ct = 0; ct < 4; ++ct) acc[rt][ct] = (f32x4){0.f, 0.f, 0.f, 0.f};

    for (int kc = 0; kc < NKC; ++kc) {
      bf16x8 a[RT], b[4];
#pragma unroll
      for (int rt = 0; rt < RT; ++rt)
        a[rt] = *reinterpret_cast<const bf16x8*>(
            &As[(rt * 16 + l15) * LDA + kc * 32 + lhi * 8]);
#pragma unroll
      for (int ct = 0; ct < 4; ++ct) {
        int n = wid * 64 + ct * 16 + l15;
        b[ct] = *reinterpret_cast<const bf16x8*>(
            Bp + ((size_t)(kc * 4 + lhi) * 256 + n) * 8);
      }
#pragma unroll
      for (int rt = 0; rt < RT; ++rt)
#pragma unroll
        for (int ct = 0; ct < 4; ++ct)
          acc[rt][ct] = __builtin_amdgcn_mfma_f32_16x16x32_bf16(a[rt], b[ct],
                                                                acc[rt][ct], 0, 0, 0);
    }

#pragma unroll
    for (int rt = 0; rt < RT; ++rt) {
#pragma unroll
      for (int ct = 0; ct < 4; ++ct) {
        int col = wid * 64 + ct * 16 + l15;
        float bv = bias[col];
#pragma unroll
        for (int r = 0; r < 4; ++r) {
          int row = row0 + rt * 16 + lhi * 4 + r;
          if (row < M) {
            float v = acc[rt][ct][r] + bv;
            if (RELU) v = fmaxf(v, 0.f);
            out[(size_t)row * 256 + col] = v;
          }
        }
      }
    }
  }
}

// ------- final: fused gather2 + dual GEMM (512 -> 47) + log_softmax -------
__global__ __launch_bounds__(64) void final_fused_k(
    const float* __restrict__ h1, const int* __restrict__ ss,
    const int* __restrict__ rs, const float* __restrict__ Wl,
    const float* __restrict__ Wr, const float* __restrict__ bb,
    float* __restrict__ out, int rep) {
  __shared__ float sm[4][256];
  __shared__ float sx[4][256];
  const int i0 = blockIdx.x * 4;
  const int f = threadIdx.x;
#pragma unroll 1
  for (int it = 0; it < rep; ++it) {
    __syncthreads();
#pragma unroll
    for (int r = 0; r < 4; ++r) {
      const int i = i0 + r;
      const int lo = rs[i];
      const int hi = rs[i + 1];
      float a0 = 0.f, a1 = 0.f, a2 = 0.f, a3 = 0.f;
      for (int e = lo; e < hi; ++e) {
        const float* p = h1 + (size_t)ss[e] * 256;
        a0 += p[f]; a1 += p[f + 64]; a2 += p[f + 128]; a3 += p[f + 192];
      }
      const float inv = 1.f / (float)max(hi - lo, 1);
      sm[r][f] = a0 * inv; sm[r][f + 64] = a1 * inv;
      sm[r][f + 128] = a2 * inv; sm[r][f + 192] = a3 * inv;
      const float* q = h1 + (size_t)i * 256;
      sx[r][f] = q[f]; sx[r][f + 64] = q[f + 64];
      sx[r][f + 128] = q[f + 128]; sx[r][f + 192] = q[f + 192];
    }
    __syncthreads();

    const int j = f;
    float acc[4] = {-1e30f, -1e30f, -1e30f, -1e30f};
    if (j < 47) {
      float b = bb[j];
      acc[0] = b; acc[1] = b; acc[2] = b; acc[3] = b;
      for (int k = 0; k < 256; ++k) {
        float wl = Wl[k * 47 + j];
        float wr = Wr[k * 47 + j];
#pragma unroll
        for (int r = 0; r < 4; ++r) acc[r] += sm[r][k] * wl + sx[r][k] * wr;
      }
    }
#pragma unroll
    for (int r = 0; r < 4; ++r) {
      float m = acc[r];
#pragma unroll
      for (int off = 32; off; off >>= 1) m = fmaxf(m, __shfl_xor(m, off));
      float e = (j < 47) ? expf(acc[r] - m) : 0.f;
      float s = e;
#pragma unroll
      for (int off = 32; off; off >>= 1) s += __shfl_xor(s, off);
      if (j < 47) out[(size_t)(i0 + r) * 47 + j] = acc[r] - m - logf(s);
    }
  }
}

extern "C" void kernel_launch(void* const* d_in, const int* in_sizes, int n_in,
                              void* d_out, int out_size, void* d_ws, size_t ws_size,
                              hipStream_t stream) {
  const float* x    = (const float*)d_in[0];
  const int*   src0 = (const int*)d_in[1];
  const int*   dst0 = (const int*)d_in[2];
  const int*   src1 = (const int*)d_in[3];
  const int*   dst1 = (const int*)d_in[4];
  const int*   src2 = (const int*)d_in[5];
  const int*   dst2 = (const int*)d_in[6];
  const float* Wl0  = (const float*)d_in[7];
  const float* Wr0  = (const float*)d_in[8];
  const float* b0   = (const float*)d_in[9];
  const float* Wl1  = (const float*)d_in[10];
  const float* Wr1  = (const float*)d_in[11];
  const float* b1   = (const float*)d_in[12];
  const float* Wl2  = (const float*)d_in[13];
  const float* Wr2  = (const float*)d_in[14];
  const float* b2   = (const float*)d_in[15];
  float* out = (float*)d_out;

  const int E0 = in_sizes[1];  // 900000
  const int E1 = in_sizes[3];  // 60000
  const int E2 = in_sizes[5];  // 5120
  const int N0 = 60000, N1 = 6000, N2 = 1024;

  // ---- workspace carve-up ----
  char* base = (char*)d_ws;
  unsigned short* am0 = (unsigned short*)(base);            // 60032 x 224 bf16
  unsigned short* bm0 = (unsigned short*)(base + 26894336); // 28x256x8 bf16
  float* h0           = (float*)(base + 27009024);          // 60032 x 256 f32
  unsigned short* am1 = (unsigned short*)(base + 88481792); // 6016 x 512 bf16
  unsigned short* bm1 = (unsigned short*)(base + 94642176); // 64x256x8 bf16
  float* h1           = (float*)(base + 94904320);          // 6016 x 256 f32
  int* iw   = (int*)(base + 102113280);
  int* row0 = iw;                       // 60001
  int* row1 = row0 + 60001;             // 6001
  int* row2 = row1 + 6001;              // 1025
  int* cnt0 = row2 + 1025;              // 60000 } contiguous: one memset
  int* cnt1 = cnt0 + 60000;             // 6000  }
  int* cnt2 = cnt1 + 6000;              // 1024  }
  int* cur0 = cnt2 + 1024;              // 60000
  int* cur1 = cur0 + 60000;             // 6000
  int* cur2 = cur1 + 6000;              // 1024
  int* ss0  = cur2 + 1024;              // 900000
  int* ss1  = ss0 + 900000;             // 60000
  int* ss2  = ss1 + 60000;              // 5120

  hipMemsetAsync(cnt0, 0, (size_t)67024 * sizeof(int), stream);

  const int ET = E0 + E1 + E2;
  hist3_k<<<(ET + 255) / 256, 256, 0, stream>>>(dst0, dst1, dst2, cnt0, cnt1, cnt2,
                                                E0, E1, E2);
  scan3_k<<<3, 1024, 0, stream>>>(cnt0, row0, cur0, cnt1, row1, cur1,
                                  cnt2, row2, cur2, N0, N1, N2, /*rep=*/24);
  fill3_k<<<(ET + 255) / 256, 256, 0, stream>>>(src0, dst0, src1, dst1, src2, dst2,
                                                cur0, cur1, cur2, ss0, ss1, ss2,
                                                E0, E1, E2);
  pack2_k<<<224 + 512, 256, 0, stream>>>(Wl0, Wr0, bm0, Wl1, Wr1, bm1);

  // ---- Layer 0 ----
  gather_fused_k<100, 224, 112><<<(N0 * 64 + 255) / 256, 256, 0, stream>>>(
      x, x, ss0, row0, am0, N0, /*rep=*/1);
  gemm_mfma_k<224, 64, true><<<(N0 + 63) / 64, 256, 0, stream>>>(
      am0, bm0, b0, h0, N0, /*rep=*/12);

  // ---- Layer 1 ----
  gather_fused_k<256, 512, 256><<<(N1 * 64 + 255) / 256, 256, 0, stream>>>(
      h0, h0, ss1, row1, am1, N1, /*rep=*/24);
  gemm_mfma_k<512, 32, true><<<(N1 + 31) / 32, 256, 0, stream>>>(
      am1, bm1, b1, h1, N1, /*rep=*/48);

  // ---- Layer 2 (fused final) ----
  final_fused_k<<<N2 / 4, 64, 0, stream>>>(h1, ss2, row2, Wl2, Wr2, b2, out,
                                           /*rep=*/48);
}

// Round 7
// 304.621 us; speedup vs baseline: 14.6191x; 14.6191x over previous
//
#include <hip/hip_runtime.h>
#include <hip/hip_bf16.h>

// GraphSAGE 3-layer, gather-based CSR + bf16-MFMA GEMMs.
// Round 7: parallel segmented scan (tilesum + scanwrite, 132 blocks) replaces
// the 3-block scan3_k (121 µs -> ~15 µs). Rest identical to round 4.
//
// Tile geometry: 512 elements/tile.
//   layer0: cnt[0..60000)      tiles [0,118)
//   layer1: cnt[60000..66000)  tiles [118,130)
//   layer2: cnt[66000..67024)  tiles [130,132)

typedef short bf16x8 __attribute__((ext_vector_type(8)));
typedef float f32x4 __attribute__((ext_vector_type(4)));

static __device__ __forceinline__ unsigned short f2bf(float f) {
  unsigned u = __float_as_uint(f);
  unsigned r = u + 0x7FFFu + ((u >> 16) & 1u);  // RNE
  return (unsigned short)(r >> 16);
}

// ---------------- CSR build ----------------
__global__ __launch_bounds__(256) void hist3_k(
    const int* __restrict__ d0, const int* __restrict__ d1, const int* __restrict__ d2,
    int* __restrict__ c0, int* __restrict__ c1, int* __restrict__ c2,
    int E0, int E1, int E2) {
  int t = blockIdx.x * 256 + threadIdx.x;
  if (t < E0) atomicAdd(&c0[d0[t]], 1);
  else if (t < E0 + E1) atomicAdd(&c1[d1[t - E0]], 1);
  else if (t < E0 + E1 + E2) atomicAdd(&c2[d2[t - E0 - E1]], 1);
}

struct TileGeom { int tin, goff, n, tbeg, T; };
static __device__ __forceinline__ TileGeom tile_geom(int b) {
  TileGeom g;
  if (b < 118)      { g.tin = b;       g.goff = 0;     g.n = 60000; g.tbeg = 0;   g.T = 118; }
  else if (b < 130) { g.tin = b - 118; g.goff = 60000; g.n = 6000;  g.tbeg = 118; g.T = 12; }
  else              { g.tin = b - 130; g.goff = 66000; g.n = 1024;  g.tbeg = 130; g.T = 2; }
  return g;
}

// per-tile sums of cnt (contiguous cnt0|cnt1|cnt2)
__global__ __launch_bounds__(256) void tilesum_k(const int* __restrict__ cnt,
                                                 int* __restrict__ tsum) {
  __shared__ int red[256];
  const TileGeom g = tile_geom(blockIdx.x);
  const int tid = threadIdx.x;
  const int i0 = g.tin * 512 + 2 * tid;
  int s = 0;
  if (i0 < g.n) s += cnt[g.goff + i0];
  if (i0 + 1 < g.n) s += cnt[g.goff + i0 + 1];
  red[tid] = s;
  __syncthreads();
  for (int off = 128; off; off >>= 1) {
    if (tid < off) red[tid] += red[tid + off];
    __syncthreads();
  }
  if (tid == 0) tsum[blockIdx.x] = red[0];
}

// per-tile: prefix over earlier tiles (same layer) + in-LDS 512-elem scan,
// writes row_start and cursor (and row[n] for the last tile of each layer).
__global__ __launch_bounds__(256) void scanwrite_k(
    const int* __restrict__ cnt, const int* __restrict__ tsum,
    int* __restrict__ row0, int* __restrict__ cur0,
    int* __restrict__ row1, int* __restrict__ cur1,
    int* __restrict__ row2, int* __restrict__ cur2) {
  __shared__ int sc[256];
  const int b = blockIdx.x;
  const TileGeom g = tile_geom(b);
  const int tid = threadIdx.x;
  int* row = (b < 118) ? row0 : (b < 130 ? row1 : row2);
  int* cur = (b < 118) ? cur0 : (b < 130 ? cur1 : cur2);

  // prefix = sum of tsum[tbeg .. b)
  int p = 0;
  for (int t = g.tbeg + tid; t < b; t += 256) p += tsum[t];
  sc[tid] = p;
  __syncthreads();
  for (int off = 128; off; off >>= 1) {
    if (tid < off) sc[tid] += sc[tid + off];
    __syncthreads();
  }
  const int pref = sc[0];
  __syncthreads();

  // 512-element pair scan
  const int i0 = g.tin * 512 + 2 * tid;
  const int e0 = (i0 < g.n) ? cnt[g.goff + i0] : 0;
  const int e1 = (i0 + 1 < g.n) ? cnt[g.goff + i0 + 1] : 0;
  sc[tid] = e0 + e1;
  __syncthreads();
  for (int off = 1; off < 256; off <<= 1) {
    int v = (tid >= off) ? sc[tid - off] : 0;
    __syncthreads();
    sc[tid] += v;
    __syncthreads();
  }
  const int excl = sc[tid] - (e0 + e1);
  const int o0 = pref + excl;
  const int o1 = o0 + e0;
  if (i0 < g.n) { row[i0] = o0; cur[i0] = o0; }
  if (i0 + 1 < g.n) { row[i0 + 1] = o1; cur[i0 + 1] = o1; }
  if (g.tin == g.T - 1 && tid == 255) row[g.n] = pref + sc[255];
}

__global__ __launch_bounds__(256) void fill3_k(
    const int* __restrict__ s0, const int* __restrict__ d0,
    const int* __restrict__ s1, const int* __restrict__ d1,
    const int* __restrict__ s2, const int* __restrict__ d2,
    int* __restrict__ u0, int* __restrict__ u1, int* __restrict__ u2,
    int* __restrict__ o0, int* __restrict__ o1, int* __restrict__ o2,
    int E0, int E1, int E2) {
  int t = blockIdx.x * 256 + threadIdx.x;
  if (t < E0) {
    int pos = atomicAdd(&u0[d0[t]], 1);
    o0[pos] = s0[t];
  } else if (t < E0 + E1) {
    int e = t - E0;
    int pos = atomicAdd(&u1[d1[e]], 1);
    o1[pos] = s1[e];
  } else if (t < E0 + E1 + E2) {
    int e = t - E0 - E1;
    int pos = atomicAdd(&u2[d2[e]], 1);
    o2[pos] = s2[e];
  }
}

// ------------- gather-mean + self-row conversion, bf16 A-matrix out -------------
template <int D, int PITCH, int XOFF>
__global__ __launch_bounds__(256) void gather_fused_k(
    const float* __restrict__ x, const float* __restrict__ xt,
    const int* __restrict__ ss, const int* __restrict__ rs,
    unsigned short* __restrict__ am, int n) {
  int idx = blockIdx.x * 256 + threadIdx.x;
  int w = idx >> 6;
  int f = idx & 63;
  if (w >= n) return;
  const int lo = rs[w];
  const int hi = rs[w + 1];
  constexpr int NR = (D + 63) / 64;
  float acc[NR];
#pragma unroll
  for (int r = 0; r < NR; ++r) acc[r] = 0.f;
  int e = lo;
  for (; e + 4 <= hi; e += 4) {
    const float* p0 = x + (size_t)ss[e] * D;
    const float* p1 = x + (size_t)ss[e + 1] * D;
    const float* p2 = x + (size_t)ss[e + 2] * D;
    const float* p3 = x + (size_t)ss[e + 3] * D;
#pragma unroll
    for (int r = 0; r < NR; ++r) {
      int k = f + 64 * r;
      if (k < D) acc[r] += (p0[k] + p1[k]) + (p2[k] + p3[k]);
    }
  }
  for (; e < hi; ++e) {
    const float* p0 = x + (size_t)ss[e] * D;
#pragma unroll
    for (int r = 0; r < NR; ++r) {
      int k = f + 64 * r;
      if (k < D) acc[r] += p0[k];
    }
  }
  const float inv = 1.f / (float)max(hi - lo, 1);
  unsigned short* arow = am + (size_t)w * PITCH;
#pragma unroll
  for (int r = 0; r < NR; ++r) {
    int k = f + 64 * r;
    if (k < D) arow[k] = f2bf(acc[r] * inv);
  }
  const float* xrow = xt + (size_t)w * D;
#pragma unroll
  for (int r = 0; r < NR; ++r) {
    int k = f + 64 * r;
    if (k < D) arow[XOFF + k] = f2bf(xrow[k]);
  }
}

// ------------- B packing for both layers -------------
__global__ __launch_bounds__(256) void pack2_k(
    const float* __restrict__ Wl0, const float* __restrict__ Wr0,
    unsigned short* __restrict__ bm0,
    const float* __restrict__ Wl1, const float* __restrict__ Wr1,
    unsigned short* __restrict__ bm1) {
  int b = blockIdx.x;
  int n = threadIdx.x;
  if (b < 224) {
    int k = b;
    float v = 0.f;
    if (k < 100) v = Wl0[(size_t)k * 256 + n];
    else if (k >= 112 && k < 212) v = Wr0[(size_t)(k - 112) * 256 + n];
    bm0[(((size_t)(k >> 3) * 256) + n) * 8 + (k & 7)] = f2bf(v);
  } else {
    int k = b - 224;
    float v = (k < 256) ? Wl1[(size_t)k * 256 + n] : Wr1[(size_t)(k - 256) * 256 + n];
    bm1[(((size_t)(k >> 3) * 256) + n) * 8 + (k & 7)] = f2bf(v);
  }
}

// ------------- MFMA GEMM -------------
template <int KPAD, int MBLK, bool RELU>
__global__ __launch_bounds__(256) void gemm_mfma_k(
    const unsigned short* __restrict__ A, const unsigned short* __restrict__ Bp,
    const float* __restrict__ bias, float* __restrict__ out, int M) {
  constexpr int LDA = KPAD + 8;
  constexpr int CPR = KPAD / 8;
  constexpr int RT = MBLK / 16;
  constexpr int NKC = KPAD / 32;
  __shared__ unsigned short As[MBLK * LDA];

  const int row0 = blockIdx.x * MBLK;
  for (int t = threadIdx.x; t < MBLK * CPR; t += 256) {
    int r = t / CPR;
    int c = t - r * CPR;
    const uint4 v = *reinterpret_cast<const uint4*>(A + (size_t)(row0 + r) * KPAD + c * 8);
    *reinterpret_cast<uint4*>(&As[r * LDA + c * 8]) = v;
  }
  __syncthreads();

  const int wid = threadIdx.x >> 6;
  const int l = threadIdx.x & 63;
  const int l15 = l & 15;
  const int lhi = l >> 4;

  f32x4 acc[RT][4];
#pragma unroll
  for (int rt = 0; rt < RT; ++rt)
#pragma unroll
    for (int ct = 0; ct < 4; ++ct) acc[rt][ct] = (f32x4){0.f, 0.f, 0.f, 0.f};

  for (int kc = 0; kc < NKC; ++kc) {
    bf16x8 a[RT], b[4];
#pragma unroll
    for (int rt = 0; rt < RT; ++rt)
      a[rt] = *reinterpret_cast<const bf16x8*>(
          &As[(rt * 16 + l15) * LDA + kc * 32 + lhi * 8]);
#pragma unroll
    for (int ct = 0; ct < 4; ++ct) {
      int n = wid * 64 + ct * 16 + l15;
      b[ct] = *reinterpret_cast<const bf16x8*>(
          Bp + ((size_t)(kc * 4 + lhi) * 256 + n) * 8);
    }
#pragma unroll
    for (int rt = 0; rt < RT; ++rt)
#pragma unroll
      for (int ct = 0; ct < 4; ++ct)
        acc[rt][ct] = __builtin_amdgcn_mfma_f32_16x16x32_bf16(a[rt], b[ct],
                                                              acc[rt][ct], 0, 0, 0);
  }

#pragma unroll
  for (int rt = 0; rt < RT; ++rt) {
#pragma unroll
    for (int ct = 0; ct < 4; ++ct) {
      int col = wid * 64 + ct * 16 + l15;
      float bv = bias[col];
#pragma unroll
      for (int r = 0; r < 4; ++r) {
        int row = row0 + rt * 16 + lhi * 4 + r;
        if (row < M) {
          float v = acc[rt][ct][r] + bv;
          if (RELU) v = fmaxf(v, 0.f);
          out[(size_t)row * 256 + col] = v;
        }
      }
    }
  }
}

// ------- final: fused gather2 + dual GEMM (512 -> 47) + log_softmax -------
__global__ __launch_bounds__(64) void final_fused_k(
    const float* __restrict__ h1, const int* __restrict__ ss,
    const int* __restrict__ rs, const float* __restrict__ Wl,
    const float* __restrict__ Wr, const float* __restrict__ bb,
    float* __restrict__ out) {
  __shared__ float sm[4][256];
  __shared__ float sx[4][256];
  const int i0 = blockIdx.x * 4;
  const int f = threadIdx.x;
#pragma unroll
  for (int r = 0; r < 4; ++r) {
    const int i = i0 + r;
    const int lo = rs[i];
    const int hi = rs[i + 1];
    float a0 = 0.f, a1 = 0.f, a2 = 0.f, a3 = 0.f;
    for (int e = lo; e < hi; ++e) {
      const float* p = h1 + (size_t)ss[e] * 256;
      a0 += p[f]; a1 += p[f + 64]; a2 += p[f + 128]; a3 += p[f + 192];
    }
    const float inv = 1.f / (float)max(hi - lo, 1);
    sm[r][f] = a0 * inv; sm[r][f + 64] = a1 * inv;
    sm[r][f + 128] = a2 * inv; sm[r][f + 192] = a3 * inv;
    const float* q = h1 + (size_t)i * 256;
    sx[r][f] = q[f]; sx[r][f + 64] = q[f + 64];
    sx[r][f + 128] = q[f + 128]; sx[r][f + 192] = q[f + 192];
  }
  __syncthreads();

  const int j = f;
  float acc[4] = {-1e30f, -1e30f, -1e30f, -1e30f};
  if (j < 47) {
    float b = bb[j];
    acc[0] = b; acc[1] = b; acc[2] = b; acc[3] = b;
    for (int k = 0; k < 256; ++k) {
      float wl = Wl[k * 47 + j];
      float wr = Wr[k * 47 + j];
#pragma unroll
      for (int r = 0; r < 4; ++r) acc[r] += sm[r][k] * wl + sx[r][k] * wr;
    }
  }
#pragma unroll
  for (int r = 0; r < 4; ++r) {
    float m = acc[r];
#pragma unroll
    for (int off = 32; off; off >>= 1) m = fmaxf(m, __shfl_xor(m, off));
    float e = (j < 47) ? expf(acc[r] - m) : 0.f;
    float s = e;
#pragma unroll
    for (int off = 32; off; off >>= 1) s += __shfl_xor(s, off);
    if (j < 47) out[(size_t)(i0 + r) * 47 + j] = acc[r] - m - logf(s);
  }
}

extern "C" void kernel_launch(void* const* d_in, const int* in_sizes, int n_in,
                              void* d_out, int out_size, void* d_ws, size_t ws_size,
                              hipStream_t stream) {
  const float* x    = (const float*)d_in[0];
  const int*   src0 = (const int*)d_in[1];
  const int*   dst0 = (const int*)d_in[2];
  const int*   src1 = (const int*)d_in[3];
  const int*   dst1 = (const int*)d_in[4];
  const int*   src2 = (const int*)d_in[5];
  const int*   dst2 = (const int*)d_in[6];
  const float* Wl0  = (const float*)d_in[7];
  const float* Wr0  = (const float*)d_in[8];
  const float* b0   = (const float*)d_in[9];
  const float* Wl1  = (const float*)d_in[10];
  const float* Wr1  = (const float*)d_in[11];
  const float* b1   = (const float*)d_in[12];
  const float* Wl2  = (const float*)d_in[13];
  const float* Wr2  = (const float*)d_in[14];
  const float* b2   = (const float*)d_in[15];
  float* out = (float*)d_out;

  const int E0 = in_sizes[1];  // 900000
  const int E1 = in_sizes[3];  // 60000
  const int E2 = in_sizes[5];  // 5120
  const int N0 = 60000, N1 = 6000, N2 = 1024;

  // ---- workspace carve-up ----
  char* base = (char*)d_ws;
  unsigned short* am0 = (unsigned short*)(base);            // 60032 x 224 bf16
  unsigned short* bm0 = (unsigned short*)(base + 26894336); // 28x256x8 bf16
  float* h0           = (float*)(base + 27009024);          // 60032 x 256 f32
  unsigned short* am1 = (unsigned short*)(base + 88481792); // 6016 x 512 bf16
  unsigned short* bm1 = (unsigned short*)(base + 94642176); // 64x256x8 bf16
  float* h1           = (float*)(base + 94904320);          // 6016 x 256 f32
  int* iw   = (int*)(base + 102113280);
  int* row0 = iw;                       // 60001
  int* row1 = row0 + 60001;             // 6001
  int* row2 = row1 + 6001;              // 1025
  int* cnt0 = row2 + 1025;              // 60000 } contiguous: one memset
  int* cnt1 = cnt0 + 60000;             // 6000  }
  int* cnt2 = cnt1 + 6000;              // 1024  }
  int* cur0 = cnt2 + 1024;              // 60000
  int* cur1 = cur0 + 60000;             // 6000
  int* cur2 = cur1 + 6000;              // 1024
  int* ss0  = cur2 + 1024;              // 900000
  int* ss1  = ss0 + 900000;             // 60000
  int* ss2  = ss1 + 60000;              // 5120
  int* tsum = ss2 + 5120;               // 132

  hipMemsetAsync(cnt0, 0, (size_t)67024 * sizeof(int), stream);

  const int ET = E0 + E1 + E2;
  hist3_k<<<(ET + 255) / 256, 256, 0, stream>>>(dst0, dst1, dst2, cnt0, cnt1, cnt2,
                                                E0, E1, E2);
  tilesum_k<<<132, 256, 0, stream>>>(cnt0, tsum);
  scanwrite_k<<<132, 256, 0, stream>>>(cnt0, tsum, row0, cur0, row1, cur1,
                                       row2, cur2);
  fill3_k<<<(ET + 255) / 256, 256, 0, stream>>>(src0, dst0, src1, dst1, src2, dst2,
                                                cur0, cur1, cur2, ss0, ss1, ss2,
                                                E0, E1, E2);
  pack2_k<<<224 + 512, 256, 0, stream>>>(Wl0, Wr0, bm0, Wl1, Wr1, bm1);

  // ---- Layer 0 ----
  gather_fused_k<100, 224, 112><<<(N0 * 64 + 255) / 256, 256, 0, stream>>>(
      x, x, ss0, row0, am0, N0);
  gemm_mfma_k<224, 64, true><<<(N0 + 63) / 64, 256, 0, stream>>>(
      am0, bm0, b0, h0, N0);

  // ---- Layer 1 ----
  gather_fused_k<256, 512, 256><<<(N1 * 64 + 255) / 256, 256, 0, stream>>>(
      h0, h0, ss1, row1, am1, N1);
  gemm_mfma_k<512, 32, true><<<(N1 + 31) / 32, 256, 0, stream>>>(
      am1, bm1, b1, h1, N1);

  // ---- Layer 2 (fused final) ----
  final_fused_k<<<N2 / 4, 64, 0, stream>>>(h1, ss2, row2, Wl2, Wr2, b2, out);
}